// Round 1
// baseline (3299.490 us; speedup 1.0000x reference)
//
#include <hip/hip_runtime.h>
#include <math.h>

#define N_NODES 100000
#define N_EDGES 800000
#define D_IN    100
#define T_DIM   100
#define M_DIM   172
#define ED_DIM  272
#define HC      100
#define CHD     50

// ---------------- K1: node projections q,k,v,s = x@W + b ----------------
#define NPB 32
__global__ __launch_bounds__(256) void node_proj(
    const float* __restrict__ x,
    const float* __restrict__ Wq, const float* __restrict__ bq,
    const float* __restrict__ Wk, const float* __restrict__ bk,
    const float* __restrict__ Wv, const float* __restrict__ bv,
    const float* __restrict__ Ws, const float* __restrict__ bs,
    float* __restrict__ qo, float* __restrict__ ko,
    float* __restrict__ vo, float* __restrict__ so)
{
    __shared__ __align__(16) float xs[NPB][D_IN];
    __shared__ float Wl[D_IN * HC];
    const int t  = threadIdx.x;
    const int n0 = blockIdx.x * NPB;

    for (int idx = t; idx < NPB * D_IN; idx += 256) {
        int n = idx / D_IN, i = idx - n * D_IN;
        xs[n][i] = x[(size_t)(n0 + n) * D_IN + i];
    }

    const float* Wm[4] = {Wq, Wk, Wv, Ws};
    const float* bm[4] = {bq, bk, bv, bs};
    float*       om[4] = {qo, ko, vo, so};

    const int ng   = t >> 6;    // wave id: nodes ng*8 .. ng*8+7 (same for all lanes of a wave)
    const int lane = t & 63;    // ch0 = lane, ch1 = lane+64 (if <100)
    const bool has2 = (lane + 64) < HC;

    for (int m = 0; m < 4; ++m) {
        __syncthreads();
        const float* W = Wm[m];
        for (int idx = t; idx < D_IN * HC; idx += 256) Wl[idx] = W[idx];
        __syncthreads();

        float acc[8][2];
        #pragma unroll
        for (int j = 0; j < 8; ++j) { acc[j][0] = 0.f; acc[j][1] = 0.f; }

        for (int i = 0; i < D_IN; i += 4) {
            float4 xv[8];
            #pragma unroll
            for (int j = 0; j < 8; ++j)
                xv[j] = *(const float4*)&xs[ng * 8 + j][i];
            #pragma unroll
            for (int kk = 0; kk < 4; ++kk) {
                float w0 = Wl[(i + kk) * HC + lane];
                float w1 = has2 ? Wl[(i + kk) * HC + lane + 64] : 0.f;
                #pragma unroll
                for (int j = 0; j < 8; ++j) {
                    float xx = ((const float*)&xv[j])[kk];
                    acc[j][0] += xx * w0;
                    acc[j][1] += xx * w1;
                }
            }
        }
        float b0 = bm[m][lane];
        float b1 = has2 ? bm[m][lane + 64] : 0.f;
        #pragma unroll
        for (int j = 0; j < 8; ++j) {
            size_t n = (size_t)(n0 + ng * 8 + j);
            om[m][n * HC + lane] = acc[j][0] + b0;
            if (has2) om[m][n * HC + lane + 64] = acc[j][1] + b1;
        }
    }
}

// ---------------- K2: edge pass (dominant) ----------------
// 64 edges/block, 320 threads. a = [cos(rel*Wt+bt) | msg] staged in LDS,
// e = a @ We via 4-edge x 5-ch register tiles, then fused exp-softmax
// numerator/denominator atomic accumulation (no segment_max needed:
// alpha std ~0.45, exp() safe; identical after normalization).
#define ET   64
#define ASTR 276   // 272 padded +4: keeps 16B alignment, breaks LDS bank aliasing
__global__ __launch_bounds__(320) void edge_pass(
    const float* __restrict__ last_update, const float* __restrict__ tarr,
    const float* __restrict__ msg,
    const float* __restrict__ Wt, const float* __restrict__ bt,
    const float* __restrict__ We,
    const int* __restrict__ ei,
    const float* __restrict__ qv, const float* __restrict__ kv,
    const float* __restrict__ vv,
    float* __restrict__ out_num, float* __restrict__ denom)
{
    __shared__ __align__(16) float a[ET * ASTR];
    __shared__ float rel[ET];
    __shared__ int   src_s[ET], dst_s[ET];
    __shared__ float ap[ET][2];
    __shared__ float exs[ET][2];

    const int t   = threadIdx.x;
    const int e0g = blockIdx.x * ET;

    if (t < ET) {
        int s = ei[e0g + t];
        int d = ei[N_EDGES + e0g + t];
        src_s[t] = s; dst_s[t] = d;
        rel[t] = last_update[s] - tarr[e0g + t];
    }
    if (t < 2 * ET) ap[t >> 1][t & 1] = 0.f;
    __syncthreads();

    // time-encoding part of a
    for (int idx = t; idx < ET * T_DIM; idx += 320) {
        int e = idx / T_DIM, i = idx - e * T_DIM;
        a[e * ASTR + i] = __cosf(rel[e] * Wt[i] + bt[i]);
    }
    // msg part of a (coalesced stream, 550 MB total)
    for (int idx = t; idx < ET * M_DIM; idx += 320) {
        int e = idx / M_DIM, j = idx - e * M_DIM;
        a[e * ASTR + T_DIM + j] = msg[(size_t)(e0g + e) * M_DIM + j];
    }
    __syncthreads();

    const int eq = t / 20, cq = t - eq * 20;   // 16 edge-quads x 20 ch-tiles
    const int e0 = eq * 4, c0 = cq * 5;
    const int head = cq / 10;                  // each 5-ch tile lies in one head

    float acc[4][5];
    #pragma unroll
    for (int j = 0; j < 4; ++j)
        #pragma unroll
        for (int c = 0; c < 5; ++c) acc[j][c] = 0.f;

    for (int k = 0; k < ED_DIM; k += 4) {
        float4 av[4];
        #pragma unroll
        for (int j = 0; j < 4; ++j)
            av[j] = *(const float4*)&a[(e0 + j) * ASTR + k];
        #pragma unroll
        for (int kk = 0; kk < 4; ++kk) {
            float w[5];
            #pragma unroll
            for (int c = 0; c < 5; ++c)
                w[c] = We[(k + kk) * HC + c0 + c];
            #pragma unroll
            for (int j = 0; j < 4; ++j) {
                float aval = ((const float*)&av[j])[kk];
                #pragma unroll
                for (int c = 0; c < 5; ++c)
                    acc[j][c] += aval * w[c];
            }
        }
    }

    // alpha partials: q[dst] . (k[src] + e), reduced across the 20 ch-tiles via LDS atomics
    #pragma unroll
    for (int j = 0; j < 4; ++j) {
        int e = e0 + j;
        int s = src_s[e], d = dst_s[e];
        float p = 0.f;
        #pragma unroll
        for (int c = 0; c < 5; ++c) {
            float qc = qv[(size_t)d * HC + c0 + c];
            float kc = kv[(size_t)s * HC + c0 + c];
            p += qc * (kc + acc[j][c]);
        }
        atomicAdd(&ap[e][head], p);
    }
    __syncthreads();

    if (t < 2 * ET) {
        int e = t >> 1, h = t & 1;
        float alpha = ap[e][h] * 0.14142135623730950488f;  // 1/sqrt(50)
        float ex = __expf(alpha);
        exs[e][h] = ex;
        atomicAdd(&denom[(size_t)dst_s[e] * 2 + h], ex);
    }
    __syncthreads();

    // numerator accumulation: out_num[dst] += ex * (v[src] + e)
    #pragma unroll
    for (int j = 0; j < 4; ++j) {
        int e = e0 + j;
        int s = src_s[e], d = dst_s[e];
        float ex = exs[e][head];
        #pragma unroll
        for (int c = 0; c < 5; ++c) {
            int ch = c0 + c;
            float val = ex * (vv[(size_t)s * HC + ch] + acc[j][c]);
            atomicAdd(&out_num[(size_t)d * HC + ch], val);
        }
    }
}

// ---------------- K3: finalize out = num/denom + s ----------------
__global__ __launch_bounds__(256) void finalize(
    const float* __restrict__ out_num, const float* __restrict__ denom,
    const float* __restrict__ s, float* __restrict__ out)
{
    int idx = blockIdx.x * 256 + threadIdx.x;
    if (idx >= N_NODES * HC) return;
    int n = idx / HC, ch = idx - n * HC, h = ch / CHD;
    float d = denom[n * 2 + h];
    float v = (d > 0.f) ? out_num[idx] / d : 0.f;
    out[idx] = v + s[idx];
}

extern "C" void kernel_launch(void* const* d_in, const int* in_sizes, int n_in,
                              void* d_out, int out_size, void* d_ws, size_t ws_size,
                              hipStream_t stream)
{
    const float* x           = (const float*)d_in[0];
    const float* last_update = (const float*)d_in[1];
    const float* t           = (const float*)d_in[2];
    const float* msg         = (const float*)d_in[3];
    const float* Wt          = (const float*)d_in[4];
    const float* bt          = (const float*)d_in[5];
    const float* Wq          = (const float*)d_in[6];
    const float* bq          = (const float*)d_in[7];
    const float* Wk          = (const float*)d_in[8];
    const float* bk          = (const float*)d_in[9];
    const float* Wv          = (const float*)d_in[10];
    const float* bv          = (const float*)d_in[11];
    const float* We          = (const float*)d_in[12];
    const float* Ws          = (const float*)d_in[13];
    const float* bs          = (const float*)d_in[14];
    const int*   ei          = (const int*)d_in[15];

    // workspace layout (floats): q,k,v,s (4 x 1e7), out_num (1e7), denom (2e5)
    // total = 50.2e6 floats = 200.8 MB
    float* ws      = (float*)d_ws;
    float* qo      = ws;
    float* ko      = qo + 10000000;
    float* vo      = ko + 10000000;
    float* so      = vo + 10000000;
    float* out_num = so + 10000000;
    float* denom   = out_num + 10000000;

    hipMemsetAsync(out_num, 0, (size_t)(10000000 + 200000) * sizeof(float), stream);

    node_proj<<<N_NODES / NPB, 256, 0, stream>>>(
        x, Wq, bq, Wk, bk, Wv, bv, Ws, bs, qo, ko, vo, so);

    edge_pass<<<N_EDGES / ET, 320, 0, stream>>>(
        last_update, t, msg, Wt, bt, We, ei, qo, ko, vo, out_num, denom);

    finalize<<<(N_NODES * HC + 255) / 256, 256, 0, stream>>>(
        out_num, denom, so, (float*)d_out);
}

// Round 2
// 2993.821 us; speedup vs baseline: 1.1021x; 1.1021x over previous
//
#include <hip/hip_runtime.h>
#include <math.h>

#define N_NODES 100000
#define N_EDGES 800000
#define D_IN    100
#define T_DIM   100
#define M_DIM   172
#define ED_DIM  272
#define HC      100
#define CHD     50

// ---------------- K1: node projections q,k,v,s = x@W + b ----------------
// grid.y selects which of the 4 matrices; removes the serial W-reload loop.
#define NPB 32
__global__ __launch_bounds__(256) void node_proj(
    const float* __restrict__ x,
    const float* __restrict__ Wq, const float* __restrict__ bq,
    const float* __restrict__ Wk, const float* __restrict__ bk,
    const float* __restrict__ Wv, const float* __restrict__ bv,
    const float* __restrict__ Ws, const float* __restrict__ bs,
    float* __restrict__ qo, float* __restrict__ ko,
    float* __restrict__ vo, float* __restrict__ so)
{
    __shared__ __align__(16) float xs[NPB][D_IN];
    __shared__ float Wl[D_IN * HC];
    const int t  = threadIdx.x;
    const int n0 = blockIdx.x * NPB;

    const float* W; const float* b; float* o;
    switch (blockIdx.y) {
        case 0: W = Wq; b = bq; o = qo; break;
        case 1: W = Wk; b = bk; o = ko; break;
        case 2: W = Wv; b = bv; o = vo; break;
        default: W = Ws; b = bs; o = so; break;
    }

    for (int idx = t; idx < NPB * D_IN; idx += 256) {
        int n = idx / D_IN, i = idx - n * D_IN;
        xs[n][i] = x[(size_t)(n0 + n) * D_IN + i];
    }
    for (int idx = t; idx < D_IN * HC; idx += 256) Wl[idx] = W[idx];
    __syncthreads();

    const int ng   = t >> 6;    // wave id: nodes ng*8 .. ng*8+7
    const int lane = t & 63;    // ch0 = lane, ch1 = lane+64 (if <100)
    const bool has2 = (lane + 64) < HC;

    float acc[8][2];
    #pragma unroll
    for (int j = 0; j < 8; ++j) { acc[j][0] = 0.f; acc[j][1] = 0.f; }

    for (int i = 0; i < D_IN; i += 4) {
        float4 xv[8];
        #pragma unroll
        for (int j = 0; j < 8; ++j)
            xv[j] = *(const float4*)&xs[ng * 8 + j][i];
        #pragma unroll
        for (int kk = 0; kk < 4; ++kk) {
            float w0 = Wl[(i + kk) * HC + lane];
            float w1 = has2 ? Wl[(i + kk) * HC + lane + 64] : 0.f;
            #pragma unroll
            for (int j = 0; j < 8; ++j) {
                float xx = ((const float*)&xv[j])[kk];
                acc[j][0] += xx * w0;
                acc[j][1] += xx * w1;
            }
        }
    }
    float b0 = b[lane];
    float b1 = has2 ? b[lane + 64] : 0.f;
    #pragma unroll
    for (int j = 0; j < 8; ++j) {
        size_t n = (size_t)(n0 + ng * 8 + j);
        o[n * HC + lane] = acc[j][0] + b0;
        if (has2) o[n * HC + lane + 64] = acc[j][1] + b1;
    }
}

// ---------------- K2: edge pass (dominant) ----------------
// 64 edges/block, 320 threads. K-dim chunked into 4x68 so the LDS a-tile is
// ~19 KB instead of 70 KB: 6 blocks/CU resident (30/32 waves) vs 1 block at
// R1 (occupancy 15% -> ~94%). a-chunk = cos part (g<100) or msg (g>=100),
// computed/loaded per chunk; e accumulated over chunks in registers.
#define ET   64
#define KC   68    // 272 = 4*68
#define KSTR 76    // row stride: 4-row stride = 304 = 16 mod 32 banks (no 4-way conflict)
__global__ __launch_bounds__(320) void edge_pass(
    const float* __restrict__ last_update, const float* __restrict__ tarr,
    const float* __restrict__ msg,
    const float* __restrict__ Wt, const float* __restrict__ bt,
    const float* __restrict__ We,
    const int* __restrict__ ei,
    const float* __restrict__ qv, const float* __restrict__ kv,
    const float* __restrict__ vv,
    float* __restrict__ out_num, float* __restrict__ denom)
{
    __shared__ __align__(16) float a[ET * KSTR];   // 19456 B
    __shared__ float rel[ET];
    __shared__ int   src_s[ET], dst_s[ET];
    __shared__ float ap[ET][2];
    __shared__ float exs[ET][2];

    const int t   = threadIdx.x;
    const int e0g = blockIdx.x * ET;

    if (t < ET) {
        int s = ei[e0g + t];
        int d = ei[N_EDGES + e0g + t];
        src_s[t] = s; dst_s[t] = d;
        rel[t] = last_update[s] - tarr[e0g + t];
    }
    if (t < 2 * ET) ap[t >> 1][t & 1] = 0.f;

    const int eq = t / 20, cq = t - eq * 20;   // 16 edge-quads x 20 ch-tiles
    const int e0 = eq * 4, c0 = cq * 5;
    const int head = cq / 10;

    float acc[4][5];
    #pragma unroll
    for (int j = 0; j < 4; ++j)
        #pragma unroll
        for (int c = 0; c < 5; ++c) acc[j][c] = 0.f;

    for (int ch = 0; ch < 4; ++ch) {
        const int g0 = ch * KC;
        __syncthreads();   // 1st iter: protects rel[]; later: protects a[] reads
        for (int idx = t; idx < ET * KC; idx += 320) {
            int e = idx / KC, c = idx - e * KC;
            int g = g0 + c;
            float v;
            if (g < T_DIM) v = __cosf(rel[e] * Wt[g] + bt[g]);
            else           v = msg[(size_t)(e0g + e) * M_DIM + (g - T_DIM)];
            a[e * KSTR + c] = v;
        }
        __syncthreads();

        for (int k = 0; k < KC; k += 4) {
            float4 av[4];
            #pragma unroll
            for (int j = 0; j < 4; ++j)
                av[j] = *(const float4*)&a[(e0 + j) * KSTR + k];
            #pragma unroll
            for (int kk = 0; kk < 4; ++kk) {
                float w[5];
                #pragma unroll
                for (int c = 0; c < 5; ++c)
                    w[c] = We[(g0 + k + kk) * HC + c0 + c];
                #pragma unroll
                for (int j = 0; j < 4; ++j) {
                    float aval = ((const float*)&av[j])[kk];
                    #pragma unroll
                    for (int c = 0; c < 5; ++c)
                        acc[j][c] += aval * w[c];
                }
            }
        }
    }

    // alpha partials: q[dst] . (k[src] + e), reduced across 20 ch-tiles via LDS atomics
    #pragma unroll
    for (int j = 0; j < 4; ++j) {
        int e = e0 + j;
        int s = src_s[e], d = dst_s[e];
        float p = 0.f;
        #pragma unroll
        for (int c = 0; c < 5; ++c) {
            float qc = qv[(size_t)d * HC + c0 + c];
            float kc = kv[(size_t)s * HC + c0 + c];
            p += qc * (kc + acc[j][c]);
        }
        atomicAdd(&ap[e][head], p);
    }
    __syncthreads();

    if (t < 2 * ET) {
        int e = t >> 1, h = t & 1;
        float alpha = ap[e][h] * 0.14142135623730950488f;  // 1/sqrt(50)
        float ex = __expf(alpha);
        exs[e][h] = ex;
        atomicAdd(&denom[(size_t)dst_s[e] * 2 + h], ex);
    }
    __syncthreads();

    // numerator accumulation: out_num[dst] += ex * (v[src] + e)
    #pragma unroll
    for (int j = 0; j < 4; ++j) {
        int e = e0 + j;
        int s = src_s[e], d = dst_s[e];
        float ex = exs[e][head];
        #pragma unroll
        for (int c = 0; c < 5; ++c) {
            int chn = c0 + c;
            float val = ex * (vv[(size_t)s * HC + chn] + acc[j][c]);
            atomicAdd(&out_num[(size_t)d * HC + chn], val);
        }
    }
}

// ---------------- K3: finalize out = num/denom + s ----------------
__global__ __launch_bounds__(256) void finalize(
    const float* __restrict__ out_num, const float* __restrict__ denom,
    const float* __restrict__ s, float* __restrict__ out)
{
    int idx = blockIdx.x * 256 + threadIdx.x;
    if (idx >= N_NODES * HC) return;
    int n = idx / HC, ch = idx - n * HC, h = ch / CHD;
    float d = denom[n * 2 + h];
    float v = (d > 0.f) ? out_num[idx] / d : 0.f;
    out[idx] = v + s[idx];
}

extern "C" void kernel_launch(void* const* d_in, const int* in_sizes, int n_in,
                              void* d_out, int out_size, void* d_ws, size_t ws_size,
                              hipStream_t stream)
{
    const float* x           = (const float*)d_in[0];
    const float* last_update = (const float*)d_in[1];
    const float* t           = (const float*)d_in[2];
    const float* msg         = (const float*)d_in[3];
    const float* Wt          = (const float*)d_in[4];
    const float* bt          = (const float*)d_in[5];
    const float* Wq          = (const float*)d_in[6];
    const float* bq          = (const float*)d_in[7];
    const float* Wk          = (const float*)d_in[8];
    const float* bk          = (const float*)d_in[9];
    const float* Wv          = (const float*)d_in[10];
    const float* bv          = (const float*)d_in[11];
    const float* We          = (const float*)d_in[12];
    const float* Ws          = (const float*)d_in[13];
    const float* bs          = (const float*)d_in[14];
    const int*   ei          = (const int*)d_in[15];

    // workspace layout (floats): q,k,v,s (4 x 1e7), out_num (1e7), denom (2e5)
    float* ws      = (float*)d_ws;
    float* qo      = ws;
    float* ko      = qo + 10000000;
    float* vo      = ko + 10000000;
    float* so      = vo + 10000000;
    float* out_num = so + 10000000;
    float* denom   = out_num + 10000000;

    hipMemsetAsync(out_num, 0, (size_t)(10000000 + 200000) * sizeof(float), stream);

    dim3 npgrid(N_NODES / NPB, 4);
    node_proj<<<npgrid, 256, 0, stream>>>(
        x, Wq, bq, Wk, bk, Wv, bv, Ws, bs, qo, ko, vo, so);

    edge_pass<<<N_EDGES / ET, 320, 0, stream>>>(
        last_update, t, msg, Wt, bt, We, ei, qo, ko, vo, out_num, denom);

    finalize<<<(N_NODES * HC + 255) / 256, 256, 0, stream>>>(
        out_num, denom, so, (float*)d_out);
}